// Round 2
// baseline (143.877 us; speedup 1.0000x reference)
//
#include <hip/hip_runtime.h>

// Problem dims (hardcoded per reference setup_inputs):
//   x:   (8, 64, 64, 64)   fp32
//   ref: (8, 64, 128, 128) fp32
//   out: (8, 64, 128, 128) fp32
#define B   8
#define C   64
#define HI  64
#define WI  64
#define HO  128
#define WO  128

using short8 = __attribute__((ext_vector_type(8))) short;
using f32x4  = __attribute__((ext_vector_type(4))) float;
using i32x4  = __attribute__((ext_vector_type(4))) int;

__device__ __forceinline__ float relu(float v) { return v > 0.f ? v : 0.f; }

// round-to-nearest-even f32 -> bf16 (low 16 bits of result)
__device__ __forceinline__ unsigned bf16rne(float x) {
  unsigned u = __float_as_uint(x);
  u += 0x7FFFu + ((u >> 16) & 1u);
  return u >> 16;
}
// pack two f32 -> bf16 pair (lo in bits [15:0], hi in bits [31:16])
__device__ __forceinline__ unsigned packbf(float lo, float hi) {
  unsigned ua = __float_as_uint(lo); ua += 0x7FFFu + ((ua >> 16) & 1u);
  unsigned ub = __float_as_uint(hi); ub += 0x7FFFu + ((ub >> 16) & 1u);
  return (ua >> 16) | (ub & 0xFFFF0000u);
}

// ---------------------------------------------------------------------------
// Fully fused, 2-barrier kernel: one block = one output row (b, h).
// 1024 blocks x 512 threads (8 waves), 2 blocks/CU (73.5 KB LDS).
//
// Top:     issue conv2 B-operand loads (ref row h) straight into registers in
//          MFMA fragment layout (T14 issue-early: they complete under phase 1).
// Phase 1: stage x rows {rlo,r1} bf16-packed + W1 + W2 (scale-folded) + res
//          half-channel partial sums; pack conv2 fragments (loads done by now).
// Phase 2: conv1 MFMA -> y1 tile in LDS; conv2 MFMA from registers (no LDS
//          restage, overlaps mask); mask corner weights.
// Epilogue: out = (sum_corners wc*y1)/den + relu(conv2+bs2).
// No workspace, no third barrier, no phase-3 global->LDS->reg chain.
// b = blockIdx&7 keeps each batch's ref/x slices XCD-local (L2 affinity).
// ---------------------------------------------------------------------------
__global__ __launch_bounds__(512, 4) void k_all(
    const float* __restrict__ x,   const float* __restrict__ ref,
    const float* __restrict__ w1,  const float* __restrict__ c1b,
    const float* __restrict__ g1,  const float* __restrict__ b1v,
    const float* __restrict__ m1,  const float* __restrict__ v1,
    const float* __restrict__ w2,  const float* __restrict__ c2b,
    const float* __restrict__ g2,  const float* __restrict__ b2v,
    const float* __restrict__ m2,  const float* __restrict__ v2,
    float* __restrict__ out) {
  __shared__ __align__(16) unsigned xP[32 * 132];        // c-pair bf16, 2 x-rows
  __shared__ __align__(16) unsigned short W1s[64 * 72];  // bf16, scale-folded
  __shared__ __align__(16) unsigned short W2s[64 * 72];  // bf16, scale-folded
  __shared__ __align__(16) float y1c[64][132];           // [ch][rowsel*64+col]
  __shared__ __align__(16) float resr2[3][130][2];       // half-channel partials
  __shared__ float s_wc[4][128];
  __shared__ float s_inv[128];
  __shared__ float s_bs1[64];
  __shared__ float s_bs2[64];

  const int bx  = blockIdx.x;
  const int b   = bx & 7;            // XCD-affine
  const int h   = bx >> 3;           // 0..127
  const int tid = threadIdx.x;

  const int wid  = tid >> 6;          // 0..7
  const int lane = tid & 63;
  const int wo = wid & 3, wp = wid >> 2;   // o-tile, px-half
  const int lq = lane >> 4, ln = lane & 15;
  const int ob = wo * 16 + lq * 4;

  const int rlo = (h >= 1) ? ((h - 1) >> 1) : 0;
  int r1 = rlo + 1; if (r1 > HI - 1) r1 = HI - 1;

  // ---- conv2 B-operand raw loads -> registers (consumed after b1) ----------
  // Fragment layout identical to the old refsP path: b0[r] holds the bf16 pair
  // (ref[2*(lq*4+r)][px], ref[2*(lq*4+r)+1][px]); b1 the +32 channels.
  const float* refrow = ref + (size_t)b * C * (HO * WO) + h * WO;
  float ra[4][8], rb[4][8];
#pragma unroll
  for (int t = 0; t < 4; ++t) {
    const int px = wp * 64 + t * 16 + ln;
#pragma unroll
    for (int r = 0; r < 4; ++r) {
      const int c0 = 2 * (lq * 4 + r);
      ra[t][2 * r]     = refrow[(size_t)c0 * (HO * WO) + px];
      ra[t][2 * r + 1] = refrow[(size_t)(c0 + 1) * (HO * WO) + px];
      rb[t][2 * r]     = refrow[(size_t)(c0 + 32) * (HO * WO) + px];
      rb[t][2 * r + 1] = refrow[(size_t)(c0 + 33) * (HO * WO) + px];
    }
  }

  // ---------------- phase 1: stage x, W1, W2, biases, res partials ----------
  for (int i = tid; i < 1024; i += 512) {     // 32 c-pairs x 32 px-quads (2 rows)
    const int c2 = i >> 5, q = i & 31;
    const int row = (q < 16) ? rlo : r1;
    const int col = (q & 15) * 4;
    const float* sp = x + ((size_t)(b * C + 2 * c2) * HI + row) * WI + col;
    const float4 lo = *(const float4*)sp;
    const float4 hi = *(const float4*)(sp + (size_t)HI * WI);
    uint4 pk;
    pk.x = packbf(lo.x, hi.x); pk.y = packbf(lo.y, hi.y);
    pk.z = packbf(lo.z, hi.z); pk.w = packbf(lo.w, hi.w);
    *(uint4*)&xP[c2 * 132 + q * 4] = pk;
  }
  for (int i = tid; i < 4096; i += 512) {     // W1 scale-folded -> bf16
    const int o = i >> 6;
    const float s = g1[o] * rsqrtf(v1[o] + 1e-5f);
    W1s[o * 72 + (i & 63)] = (unsigned short)bf16rne(w1[i] * s);
  }
  for (int i = tid; i < 4096; i += 512) {     // W2 scale-folded -> bf16
    const int o = i >> 6;
    const float s = g2[o] * rsqrtf(v2[o] + 1e-5f);
    W2s[o * 72 + (i & 63)] = (unsigned short)bf16rne(w2[i] * s);
  }
  if (tid < 64) {
    float s = g1[tid] * rsqrtf(v1[tid] + 1e-5f);
    s_bs1[tid] = c1b[tid] * s + b1v[tid] - m1[tid] * s;
    s = g2[tid] * rsqrtf(v2[tid] + 1e-5f);
    s_bs2[tid] = c2b[tid] * s + b2v[tid] - m2[tid] * s;
  }
  // res partial sums: 3 rows x 64 px-pairs x {even,odd} channel halves.
  // Accumulation order bit-matches the passing kernel: even channels ascending,
  // odd channels ascending, combined as (even+odd)*(1/64) at mask read.
  if (tid < 384) {
    const int rr = tid >> 7;                  // 0..2
    const int j  = tid & 127;
    const int p  = j >> 1, half = j & 1;      // half: 0=even ch, 1=odd ch
    const int hh = h + rr - 1;
    float sx = 0.f, sy = 0.f;
    if (hh >= 0 && hh < HO) {
      const float* sp = ref + ((size_t)(b * C + half) * HO + hh) * WO + 2 * p;
#pragma unroll
      for (int k = 0; k < 32; ++k) {          // channel = half + 2k, ascending
        const float2 t = *(const float2*)&sp[(size_t)(2 * k) * (HO * WO)];
        sx += t.x; sy += t.y;
      }
    }
    resr2[rr][1 + 2 * p][half] = sx;
    resr2[rr][2 + 2 * p][half] = sy;
  } else if (tid < 396) {                     // zero the 12 border cells
    const int i2 = tid - 384;
    const int rr = i2 >> 2, idx = i2 & 3;
    resr2[rr][(idx & 1) ? 129 : 0][idx >> 1] = 0.f;
  }

  // pack conv2 fragments (raw loads have had all of phase 1 to complete)
  i32x4 cfb0[4], cfb1[4];
#pragma unroll
  for (int t = 0; t < 4; ++t)
#pragma unroll
    for (int r = 0; r < 4; ++r) {
      cfb0[t][r] = (int)packbf(ra[t][2 * r], ra[t][2 * r + 1]);
      cfb1[t][r] = (int)packbf(rb[t][2 * r], rb[t][2 * r + 1]);
    }
  __syncthreads();   // b1

  // ---------------- phase 2: conv1 MFMA -> y1c; conv2 MFMA; mask ------------
  const short8 fa0 = *(const short8*)&W1s[(wo * 16 + ln) * 72 + lq * 8];
  const short8 fa1 = *(const short8*)&W1s[(wo * 16 + ln) * 72 + 32 + lq * 8];
  const short8 fb0 = *(const short8*)&W2s[(wo * 16 + ln) * 72 + lq * 8];
  const short8 fb1 = *(const short8*)&W2s[(wo * 16 + ln) * 72 + 32 + lq * 8];

  {
    float bs1a[4];
    *(float4*)bs1a = *(const float4*)&s_bs1[ob];
#pragma unroll
    for (int t = 0; t < 4; ++t) {
      const int px = wp * 64 + t * 16 + ln;   // rowsel*64 + col
      i32x4 b0, b1;
#pragma unroll
      for (int r = 0; r < 4; ++r) {
        b0[r] = (int)xP[(lq * 4 + r) * 132 + px];
        b1[r] = (int)xP[(16 + lq * 4 + r) * 132 + px];
      }
      f32x4 a = {0.f, 0.f, 0.f, 0.f};
      a = __builtin_amdgcn_mfma_f32_16x16x32_bf16(fa0, __builtin_bit_cast(short8, b0), a, 0, 0, 0);
      a = __builtin_amdgcn_mfma_f32_16x16x32_bf16(fa1, __builtin_bit_cast(short8, b1), a, 0, 0, 0);
#pragma unroll
      for (int r = 0; r < 4; ++r)
        y1c[ob + r][px] = relu(a[r] + bs1a[r]);
    }
  }

  // conv2 MFMA straight from registers (overlaps mask; no LDS restage)
  f32x4 acc2[4];
#pragma unroll
  for (int t = 0; t < 4; ++t) {
    acc2[t] = (f32x4){0.f, 0.f, 0.f, 0.f};
    acc2[t] = __builtin_amdgcn_mfma_f32_16x16x32_bf16(fb0, __builtin_bit_cast(short8, cfb0[t]), acc2[t], 0, 0, 0);
    acc2[t] = __builtin_amdgcn_mfma_f32_16x16x32_bf16(fb1, __builtin_bit_cast(short8, cfb1[t]), acc2[t], 0, 0, 0);
  }

  // mask phase: per-pixel 4 corner weights + invden (threads 0..127)
  if (tid < 128) {
    const int w = tid;
    float u[9];
#pragma unroll
    for (int dh = 0; dh < 3; ++dh)
#pragma unroll
      for (int dw = 0; dw < 3; ++dw) {
        const float2 pr = *(const float2*)&resr2[dh][w + dw][0];
        u[dh * 3 + dw] = (pr.x + pr.y) * (1.f / 64.f);
      }
    float sum = u[0];
#pragma unroll
    for (int k = 1; k < 9; ++k) sum += u[k];
    const float ua = sum * (1.f / 9.f);
    const bool ui = (u[4] - ua) > 0.f;

    const int clo = (w >= 1) ? ((w - 1) >> 1) : 0;
    float den = 0.f;
    float wc0 = 0.f, wc1 = 0.f, wc2 = 0.f, wc3 = 0.f;
#pragma unroll
    for (int dh = 0; dh < 3; ++dh) {
      const int hh = h + dh - 1;
      const bool hv = (hh >= 0) && (hh < HO);
      const int rs = hv ? ((hh >> 1) - rlo) : 0;
#pragma unroll
      for (int dw = 0; dw < 3; ++dw) {
        const bool up = (u[dh * 3 + dw] - ua) > 0.f;
        const float mk = (up == ui) ? 1.f : 0.f;
        den += mk;
        const int ww = w + dw - 1;
        const bool wv = (ww >= 0) && (ww < WO);
        const int cs = wv ? ((ww >> 1) - clo) : 0;
        const float t = (hv && wv) ? mk : 0.f;
        const float t0 = (rs == 0) ? t : 0.f;
        const float t1 = (rs == 1) ? t : 0.f;
        wc0 += (cs == 0) ? t0 : 0.f;
        wc1 += (cs == 1) ? t0 : 0.f;
        wc2 += (cs == 0) ? t1 : 0.f;
        wc3 += (cs == 1) ? t1 : 0.f;
      }
    }
    s_wc[0][w] = wc0; s_wc[1][w] = wc1; s_wc[2][w] = wc2; s_wc[3][w] = wc3;
    s_inv[w] = 1.f / (den + 1e-6f);
  }
  __syncthreads();   // b2: y1c + mask ready

  // ---------------- epilogue -------------------------------------------------
  float bs2a[4];
  *(float4*)bs2a = *(const float4*)&s_bs2[ob];

#pragma unroll
  for (int t = 0; t < 4; ++t) {
    const int px = wp * 64 + t * 16 + ln;
    const int cl = (px >= 1) ? ((px - 1) >> 1) : 0;
    int c1 = cl + 1; if (c1 > WI - 1) c1 = WI - 1;
    const float wc0 = s_wc[0][px], wc1 = s_wc[1][px];
    const float wc2 = s_wc[2][px], wc3 = s_wc[3][px];
    const float inv = s_inv[px];

    float* op = out + (size_t)(b * C + ob) * (HO * WO) + h * WO + px;
#pragma unroll
    for (int r = 0; r < 4; ++r) {
      const float n = wc0 * y1c[ob + r][cl]      + wc1 * y1c[ob + r][c1]
                    + wc2 * y1c[ob + r][64 + cl] + wc3 * y1c[ob + r][64 + c1];
      op[(size_t)r * (HO * WO)] = n * inv + relu(acc2[t][r] + bs2a[r]);
    }
  }
}

// ---------------------------------------------------------------------------
extern "C" void kernel_launch(void* const* d_in, const int* in_sizes, int n_in,
                              void* d_out, int out_size, void* d_ws, size_t ws_size,
                              hipStream_t stream) {
  (void)in_sizes; (void)n_in; (void)out_size; (void)d_ws; (void)ws_size;
  const float* x   = (const float*)d_in[0];
  const float* ref = (const float*)d_in[1];
  const float* w1  = (const float*)d_in[2];
  const float* c1b = (const float*)d_in[3];
  const float* g1  = (const float*)d_in[4];
  const float* b1  = (const float*)d_in[5];
  const float* m1  = (const float*)d_in[6];
  const float* v1  = (const float*)d_in[7];
  const float* w2  = (const float*)d_in[8];
  const float* c2b = (const float*)d_in[9];
  const float* g2  = (const float*)d_in[10];
  const float* b2  = (const float*)d_in[11];
  const float* m2  = (const float*)d_in[12];
  const float* v2  = (const float*)d_in[13];
  float* out = (float*)d_out;

  k_all<<<B * HO, 512, 0, stream>>>(x, ref, w1, c1b, g1, b1, m1, v1,
                                    w2, c2b, g2, b2, m2, v2, out);
}

// Round 3
// 142.356 us; speedup vs baseline: 1.0107x; 1.0107x over previous
//
#include <hip/hip_runtime.h>

// Problem dims (hardcoded per reference setup_inputs):
//   x:   (8, 64, 64, 64)   fp32
//   ref: (8, 64, 128, 128) fp32
//   out: (8, 64, 128, 128) fp32
#define B   8
#define C   64
#define HI  64
#define WI  64
#define HO  128
#define WO  128

using short8 = __attribute__((ext_vector_type(8))) short;
using f32x4  = __attribute__((ext_vector_type(4))) float;
using i32x4  = __attribute__((ext_vector_type(4))) int;

__device__ __forceinline__ float relu(float v) { return v > 0.f ? v : 0.f; }

// round-to-nearest-even f32 -> bf16 (low 16 bits of result)
__device__ __forceinline__ unsigned bf16rne(float x) {
  unsigned u = __float_as_uint(x);
  u += 0x7FFFu + ((u >> 16) & 1u);
  return u >> 16;
}
// pack two f32 -> bf16 pair (lo in bits [15:0], hi in bits [31:16])
__device__ __forceinline__ unsigned packbf(float lo, float hi) {
  unsigned ua = __float_as_uint(lo); ua += 0x7FFFu + ((ua >> 16) & 1u);
  unsigned ub = __float_as_uint(hi); ub += 0x7FFFu + ((ub >> 16) & 1u);
  return (ua >> 16) | (ub & 0xFFFF0000u);
}

// ---------------------------------------------------------------------------
// Fully fused kernel, 3 blocks/CU: one block = one output row (b, h).
// 1024 blocks x 512 threads (8 waves). LDS = 53,016 B -> 3 blocks/CU.
//
// Weights: per-lane fragment loads from global (L1/L2 broadcast), packed to
//          bf16 in registers — no weight LDS, no 8K-element staging loops.
// Phase 1 (all global loads live here):
//          xP <- x rows {rlo,r1} bf16-packed; refsP (alias of y1c LDS) <- ref
//          row h bf16-packed; resr <- channel-sum partials of ref rows h-1..h+1;
//          biases; weight fragments packed in regs.
// Phase 2a: conv2 MFMA from refsP -> acc2 regs; mask corner weights (u8x4
//          packed) — then b2 (refsP reads done).
// Phase 2b: conv1 MFMA from xP -> y1 tile overwrites refsP area — then b3.
// Epilogue: out = (sum_corners wc*y1)/den + relu(acc2+bs2).
// b = blockIdx&7 keeps batches XCD-local; rows h-1,h,h+1 of the same b map to
// the same XCD (bx +- 8) so resr re-reads hit that XCD's L2.
// ---------------------------------------------------------------------------
__global__ __launch_bounds__(512, 6) void k_all(
    const float* __restrict__ x,   const float* __restrict__ ref,
    const float* __restrict__ w1,  const float* __restrict__ c1b,
    const float* __restrict__ g1,  const float* __restrict__ b1v,
    const float* __restrict__ m1,  const float* __restrict__ v1,
    const float* __restrict__ w2,  const float* __restrict__ c2b,
    const float* __restrict__ g2,  const float* __restrict__ b2v,
    const float* __restrict__ m2,  const float* __restrict__ v2,
    float* __restrict__ out) {
  __shared__ __align__(16) float    y1c[64 * 130];   // ph1/2a: refsP alias; ph2b: y1 tile
  __shared__ __align__(16) unsigned xP[32 * 130];    // c-pair bf16, 2 x-rows
  __shared__ __align__(16) float    resr[3][130];    // channel-mean*64 of ref rows
  __shared__ unsigned s_wcp[128];                    // 4 corner weights, u8 each
  __shared__ float    s_inv[128];
  __shared__ float    s_bs1[64];
  __shared__ float    s_bs2[64];

  unsigned* refsP = (unsigned*)y1c;

  const int bx  = blockIdx.x;
  const int b   = bx & 7;            // XCD-affine
  const int h   = bx >> 3;           // 0..127
  const int tid = threadIdx.x;

  const int wid  = tid >> 6;          // 0..7
  const int lane = tid & 63;
  const int wo = wid & 3, wp = wid >> 2;   // o-tile, px-half
  const int lq = lane >> 4, ln = lane & 15;
  const int ob = wo * 16 + lq * 4;
  const int ow = wo * 16 + ln;        // weight row for A-fragments

  const int rlo = (h >= 1) ? ((h - 1) >> 1) : 0;
  int r1 = rlo + 1; if (r1 > HI - 1) r1 = HI - 1;

  // ---- weight fragment loads (global, L1/L2-broadcast; consumed after b1) --
  const float4 wa0 = *(const float4*)&w1[ow * 64 + lq * 8];
  const float4 wa1 = *(const float4*)&w1[ow * 64 + lq * 8 + 4];
  const float4 wa2 = *(const float4*)&w1[ow * 64 + 32 + lq * 8];
  const float4 wa3 = *(const float4*)&w1[ow * 64 + 32 + lq * 8 + 4];
  const float4 wb0 = *(const float4*)&w2[ow * 64 + lq * 8];
  const float4 wb1 = *(const float4*)&w2[ow * 64 + lq * 8 + 4];
  const float4 wb2 = *(const float4*)&w2[ow * 64 + 32 + lq * 8];
  const float4 wb3 = *(const float4*)&w2[ow * 64 + 32 + lq * 8 + 4];
  const float g1o = g1[ow], v1o = v1[ow];
  const float g2o = g2[ow], v2o = v2[ow];

  // ---------------- phase 1: stage xP, refsP, resr, biases ------------------
  for (int i = tid; i < 1024; i += 512) {     // x: 32 c-pairs x 32 px-quads
    const int c2 = i >> 5, q = i & 31;
    const int row = (q < 16) ? rlo : r1;
    const int col = (q & 15) * 4;
    const float* sp = x + ((size_t)(b * C + 2 * c2) * HI + row) * WI + col;
    const float4 lo = *(const float4*)sp;
    const float4 hi = *(const float4*)(sp + (size_t)HI * WI);
    uint4 pk;
    pk.x = packbf(lo.x, hi.x); pk.y = packbf(lo.y, hi.y);
    pk.z = packbf(lo.z, hi.z); pk.w = packbf(lo.w, hi.w);
    *(uint4*)&xP[c2 * 130 + q * 4] = pk;
  }
  for (int i = tid; i < 1024; i += 512) {     // ref row h: 32 c-pairs x 32 quads
    const int c2 = i >> 5, q = i & 31;
    const float* sp = ref + ((size_t)(b * C + 2 * c2) * HO + h) * WO + q * 4;
    const float4 lo = *(const float4*)sp;
    const float4 hi = *(const float4*)(sp + (size_t)HO * WO);
    uint4 pk;
    pk.x = packbf(lo.x, hi.x); pk.y = packbf(lo.y, hi.y);
    pk.z = packbf(lo.z, hi.z); pk.w = packbf(lo.w, hi.w);
    *(uint4*)&refsP[c2 * 130 + q * 4] = pk;
  }
  if (tid < 192) {
    // resr: 3 rows x 64 px-pairs. Bit-exact accumulation: even channels
    // ascending, odd channels ascending, halves summed at store.
    const int rr = tid >> 6;                  // 0..2
    const int p  = tid & 63;
    const int hh = h + rr - 1;
    float sex = 0.f, sey = 0.f, sox = 0.f, soy = 0.f;
    if (hh >= 0 && hh < HO) {
      const float* sp0 = ref + ((size_t)(b * C + 0) * HO + hh) * WO + 2 * p;
      const float* sp1 = ref + ((size_t)(b * C + 1) * HO + hh) * WO + 2 * p;
#pragma unroll
      for (int k = 0; k < 32; ++k) {          // channel = 2k / 2k+1, ascending
        const float2 e = *(const float2*)&sp0[(size_t)(2 * k) * (HO * WO)];
        const float2 o = *(const float2*)&sp1[(size_t)(2 * k) * (HO * WO)];
        sex += e.x; sey += e.y;
        sox += o.x; soy += o.y;
      }
    }
    resr[rr][1 + 2 * p] = sex + sox;
    resr[rr][2 + 2 * p] = sey + soy;
  } else if (tid < 198) {                     // zero the 6 border cells
    const int i2 = tid - 192;
    resr[i2 >> 1][(i2 & 1) ? 129 : 0] = 0.f;
  }
  if (tid < 64) {
    float s = g1[tid] * rsqrtf(v1[tid] + 1e-5f);
    s_bs1[tid] = c1b[tid] * s + b1v[tid] - m1[tid] * s;
    s = g2[tid] * rsqrtf(v2[tid] + 1e-5f);
    s_bs2[tid] = c2b[tid] * s + b2v[tid] - m2[tid] * s;
  }

  // pack weight fragments (loads have had all of phase 1 to complete)
  i32x4 fa0i, fa1i, fb0i, fb1i;
  {
    const float s1 = g1o * rsqrtf(v1o + 1e-5f);
    const float s2 = g2o * rsqrtf(v2o + 1e-5f);
    fa0i[0] = (int)packbf(wa0.x * s1, wa0.y * s1);
    fa0i[1] = (int)packbf(wa0.z * s1, wa0.w * s1);
    fa0i[2] = (int)packbf(wa1.x * s1, wa1.y * s1);
    fa0i[3] = (int)packbf(wa1.z * s1, wa1.w * s1);
    fa1i[0] = (int)packbf(wa2.x * s1, wa2.y * s1);
    fa1i[1] = (int)packbf(wa2.z * s1, wa2.w * s1);
    fa1i[2] = (int)packbf(wa3.x * s1, wa3.y * s1);
    fa1i[3] = (int)packbf(wa3.z * s1, wa3.w * s1);
    fb0i[0] = (int)packbf(wb0.x * s2, wb0.y * s2);
    fb0i[1] = (int)packbf(wb0.z * s2, wb0.w * s2);
    fb0i[2] = (int)packbf(wb1.x * s2, wb1.y * s2);
    fb0i[3] = (int)packbf(wb1.z * s2, wb1.w * s2);
    fb1i[0] = (int)packbf(wb2.x * s2, wb2.y * s2);
    fb1i[1] = (int)packbf(wb2.z * s2, wb2.w * s2);
    fb1i[2] = (int)packbf(wb3.x * s2, wb3.y * s2);
    fb1i[3] = (int)packbf(wb3.z * s2, wb3.w * s2);
  }
  const short8 fa0 = __builtin_bit_cast(short8, fa0i);
  const short8 fa1 = __builtin_bit_cast(short8, fa1i);
  const short8 fb0 = __builtin_bit_cast(short8, fb0i);
  const short8 fb1 = __builtin_bit_cast(short8, fb1i);
  __syncthreads();   // b1

  // ---------------- phase 2a: conv2 MFMA from refsP; mask -------------------
  f32x4 acc2[4];
#pragma unroll
  for (int t = 0; t < 4; ++t) {
    const int px = wp * 64 + t * 16 + ln;
    i32x4 b0, b1;
#pragma unroll
    for (int r = 0; r < 4; ++r) {
      b0[r] = (int)refsP[(lq * 4 + r) * 130 + px];
      b1[r] = (int)refsP[(16 + lq * 4 + r) * 130 + px];
    }
    acc2[t] = (f32x4){0.f, 0.f, 0.f, 0.f};
    acc2[t] = __builtin_amdgcn_mfma_f32_16x16x32_bf16(fb0, __builtin_bit_cast(short8, b0), acc2[t], 0, 0, 0);
    acc2[t] = __builtin_amdgcn_mfma_f32_16x16x32_bf16(fb1, __builtin_bit_cast(short8, b1), acc2[t], 0, 0, 0);
  }

  // mask: per-pixel 4 corner weights + invden (threads 0..127)
  if (tid < 128) {
    const int w = tid;
    float u[9];
#pragma unroll
    for (int dh = 0; dh < 3; ++dh)
#pragma unroll
      for (int dw = 0; dw < 3; ++dw)
        u[dh * 3 + dw] = resr[dh][w + dw] * (1.f / 64.f);
    float sum = u[0];
#pragma unroll
    for (int k = 1; k < 9; ++k) sum += u[k];
    const float ua = sum * (1.f / 9.f);
    const bool ui = (u[4] - ua) > 0.f;

    const int clo = (w >= 1) ? ((w - 1) >> 1) : 0;
    float den = 0.f;
    unsigned wc0 = 0, wc1 = 0, wc2 = 0, wc3 = 0;
#pragma unroll
    for (int dh = 0; dh < 3; ++dh) {
      const int hh = h + dh - 1;
      const bool hv = (hh >= 0) && (hh < HO);
      const int rs = hv ? ((hh >> 1) - rlo) : 0;
#pragma unroll
      for (int dw = 0; dw < 3; ++dw) {
        const bool up = (u[dh * 3 + dw] - ua) > 0.f;
        const float mk = (up == ui) ? 1.f : 0.f;
        den += mk;
        const int ww = w + dw - 1;
        const bool wv = (ww >= 0) && (ww < WO);
        const int cs = wv ? ((ww >> 1) - clo) : 0;
        const unsigned t = (hv && wv && mk > 0.f) ? 1u : 0u;
        const unsigned t0 = (rs == 0) ? t : 0u;
        const unsigned t1 = (rs == 1) ? t : 0u;
        wc0 += (cs == 0) ? t0 : 0u;
        wc1 += (cs == 1) ? t0 : 0u;
        wc2 += (cs == 0) ? t1 : 0u;
        wc3 += (cs == 1) ? t1 : 0u;
      }
    }
    s_wcp[w] = wc0 | (wc1 << 8) | (wc2 << 16) | (wc3 << 24);
    s_inv[w] = 1.f / (den + 1e-6f);
  }
  __syncthreads();   // b2: refsP reads done -> safe to overwrite with y1 tile

  // ---------------- phase 2b: conv1 MFMA -> y1 tile -------------------------
  {
    float bs1a[4];
    *(float4*)bs1a = *(const float4*)&s_bs1[ob];
#pragma unroll
    for (int t = 0; t < 4; ++t) {
      const int px = wp * 64 + t * 16 + ln;   // rowsel*64 + col
      i32x4 b0, b1;
#pragma unroll
      for (int r = 0; r < 4; ++r) {
        b0[r] = (int)xP[(lq * 4 + r) * 130 + px];
        b1[r] = (int)xP[(16 + lq * 4 + r) * 130 + px];
      }
      f32x4 a = {0.f, 0.f, 0.f, 0.f};
      a = __builtin_amdgcn_mfma_f32_16x16x32_bf16(fa0, __builtin_bit_cast(short8, b0), a, 0, 0, 0);
      a = __builtin_amdgcn_mfma_f32_16x16x32_bf16(fa1, __builtin_bit_cast(short8, b1), a, 0, 0, 0);
#pragma unroll
      for (int r = 0; r < 4; ++r)
        y1c[(ob + r) * 130 + px] = relu(a[r] + bs1a[r]);
    }
  }
  __syncthreads();   // b3: y1 tile ready

  // ---------------- epilogue -------------------------------------------------
  float bs2a[4];
  *(float4*)bs2a = *(const float4*)&s_bs2[ob];

#pragma unroll
  for (int t = 0; t < 4; ++t) {
    const int px = wp * 64 + t * 16 + ln;
    const int cl = (px >= 1) ? ((px - 1) >> 1) : 0;
    int c1 = cl + 1; if (c1 > WI - 1) c1 = WI - 1;
    const unsigned pk = s_wcp[px];
    const float wc0 = (float)(pk & 255u);
    const float wc1 = (float)((pk >> 8) & 255u);
    const float wc2 = (float)((pk >> 16) & 255u);
    const float wc3 = (float)(pk >> 24);
    const float inv = s_inv[px];

    float* op = out + (size_t)(b * C + ob) * (HO * WO) + h * WO + px;
#pragma unroll
    for (int r = 0; r < 4; ++r) {
      const float n = wc0 * y1c[(ob + r) * 130 + cl]
                    + wc1 * y1c[(ob + r) * 130 + c1]
                    + wc2 * y1c[(ob + r) * 130 + 64 + cl]
                    + wc3 * y1c[(ob + r) * 130 + 64 + c1];
      op[(size_t)r * (HO * WO)] = n * inv + relu(acc2[t][r] + bs2a[r]);
    }
  }
}

// ---------------------------------------------------------------------------
extern "C" void kernel_launch(void* const* d_in, const int* in_sizes, int n_in,
                              void* d_out, int out_size, void* d_ws, size_t ws_size,
                              hipStream_t stream) {
  (void)in_sizes; (void)n_in; (void)out_size; (void)d_ws; (void)ws_size;
  const float* x   = (const float*)d_in[0];
  const float* ref = (const float*)d_in[1];
  const float* w1  = (const float*)d_in[2];
  const float* c1b = (const float*)d_in[3];
  const float* g1  = (const float*)d_in[4];
  const float* b1  = (const float*)d_in[5];
  const float* m1  = (const float*)d_in[6];
  const float* v1  = (const float*)d_in[7];
  const float* w2  = (const float*)d_in[8];
  const float* c2b = (const float*)d_in[9];
  const float* g2  = (const float*)d_in[10];
  const float* b2  = (const float*)d_in[11];
  const float* m2  = (const float*)d_in[12];
  const float* v2  = (const float*)d_in[13];
  float* out = (float*)d_out;

  k_all<<<B * HO, 512, 0, stream>>>(x, ref, w1, c1b, g1, b1, m1, v1,
                                    w2, c2b, g2, b2, m2, v2, out);
}

// Round 4
// 138.596 us; speedup vs baseline: 1.0381x; 1.0271x over previous
//
#include <hip/hip_runtime.h>

// Problem dims (hardcoded per reference setup_inputs):
//   x:   (8, 64, 64, 64)   fp32
//   ref: (8, 64, 128, 128) fp32
//   out: (8, 64, 128, 128) fp32
#define B   8
#define C   64
#define HI  64
#define WI  64
#define HO  128
#define WO  128

using short8 = __attribute__((ext_vector_type(8))) short;
using f32x4  = __attribute__((ext_vector_type(4))) float;
using i32x4  = __attribute__((ext_vector_type(4))) int;

__device__ __forceinline__ float relu(float v) { return v > 0.f ? v : 0.f; }

// round-to-nearest-even f32 -> bf16 (low 16 bits of result)
__device__ __forceinline__ unsigned bf16rne(float x) {
  unsigned u = __float_as_uint(x);
  u += 0x7FFFu + ((u >> 16) & 1u);
  return u >> 16;
}
// pack two f32 -> bf16 pair (lo in bits [15:0], hi in bits [31:16])
__device__ __forceinline__ unsigned packbf(float lo, float hi) {
  unsigned ua = __float_as_uint(lo); ua += 0x7FFFu + ((ua >> 16) & 1u);
  unsigned ub = __float_as_uint(hi); ub += 0x7FFFu + ((ub >> 16) & 1u);
  return (ua >> 16) | (ub & 0xFFFF0000u);
}

// ---------------------------------------------------------------------------
// Fully fused kernel, 3 blocks/CU, wave-specialized phase 1.
// One block = one output row (b, h); 1024 blocks x 512 threads (8 waves).
// LDS = 54,272 B -> 3 blocks/CU.
//
// Phase 1 (wave-specialized for memory-level parallelism):
//   all:       weight fragments (8 x float4 + 4 scalars) issued FIRST.
//   waves 0-5: resr gather only — 3 rows x 64 px-pairs x {even,odd} halves,
//              32-load chains explicitly batched 8-deep (bit-exact order).
//   waves 6-7: all x/ref -> LDS bf16 staging (coalesced) + biases.
//   all:       pack weight fragments (loads long since landed).
// Phase 2a: conv2 MFMA from refsP; mask -> {wc0..3,den} nibble-packed u32.
// Phase 2b: conv1 MFMA -> y1 tile (overwrites refsP region after b2).
// Epilogue: out = (sum_corners wc*y1)/(den+1e-6) + relu(acc2+bs2).
// Strides: y1c/refsP 132 (round-2-proven low-conflict), xP 128.
// ---------------------------------------------------------------------------
__global__ __launch_bounds__(512, 6) void k_all(
    const float* __restrict__ x,   const float* __restrict__ ref,
    const float* __restrict__ w1,  const float* __restrict__ c1b,
    const float* __restrict__ g1,  const float* __restrict__ b1v,
    const float* __restrict__ m1,  const float* __restrict__ v1,
    const float* __restrict__ w2,  const float* __restrict__ c2b,
    const float* __restrict__ g2,  const float* __restrict__ b2v,
    const float* __restrict__ m2,  const float* __restrict__ v2,
    float* __restrict__ out) {
  __shared__ __align__(16) float    y1c[64 * 132];     // ph1/2a: refsP alias; ph2b: y1
  __shared__ __align__(16) unsigned xP[32 * 128];      // c-pair bf16, 2 x-rows
  __shared__ __align__(16) float    resr2[3][128][2];  // half-channel partials
  __shared__ unsigned s_wcp[128];                      // wc0..3 + den, nibbles
  __shared__ float    s_bs1[64];
  __shared__ float    s_bs2[64];

  unsigned* refsP = (unsigned*)y1c;                    // stride 132, 16B-aligned rows

  const int bx  = blockIdx.x;
  const int b   = bx & 7;            // XCD-affine
  const int h   = bx >> 3;           // 0..127
  const int tid = threadIdx.x;

  const int wid  = tid >> 6;          // 0..7
  const int lane = tid & 63;
  const int wo = wid & 3, wp = wid >> 2;   // o-tile, px-half
  const int lq = lane >> 4, ln = lane & 15;
  const int ob = wo * 16 + lq * 4;
  const int ow = wo * 16 + ln;        // weight row for A-fragments

  const int rlo = (h >= 1) ? ((h - 1) >> 1) : 0;
  int r1 = rlo + 1; if (r1 > HI - 1) r1 = HI - 1;

  // ---- weight fragment loads issued FIRST (hidden under the gather) --------
  const float4 wa0 = *(const float4*)&w1[ow * 64 + lq * 8];
  const float4 wa1 = *(const float4*)&w1[ow * 64 + lq * 8 + 4];
  const float4 wa2 = *(const float4*)&w1[ow * 64 + 32 + lq * 8];
  const float4 wa3 = *(const float4*)&w1[ow * 64 + 32 + lq * 8 + 4];
  const float4 wb0 = *(const float4*)&w2[ow * 64 + lq * 8];
  const float4 wb1 = *(const float4*)&w2[ow * 64 + lq * 8 + 4];
  const float4 wb2 = *(const float4*)&w2[ow * 64 + 32 + lq * 8];
  const float4 wb3 = *(const float4*)&w2[ow * 64 + 32 + lq * 8 + 4];
  const float g1o = g1[ow], v1o = v1[ow];
  const float g2o = g2[ow], v2o = v2[ow];

  // ---------------- phase 1: wave-specialized -------------------------------
  if (tid < 384) {
    // resr gather: rr = row (h-1..h+1), p = px-pair, half = even/odd channels.
    // Bit-exact: even channels ascending (half 0), odd ascending (half 1);
    // halves combined at mask read as (e+o)*(1/64) — round-0 lineage.
    const int rr  = tid >> 7;                 // 0..2
    const int rem = tid & 127;
    const int p = rem >> 1, half = rem & 1;
    const int hh = h + rr - 1;
    float sx = 0.f, sy = 0.f;
    if (hh >= 0 && hh < HO) {
      const float* sp = ref + ((size_t)(b * C + half) * HO + hh) * WO + 2 * p;
      float2 buf[8];
#pragma unroll
      for (int kb = 0; kb < 4; ++kb) {        // 4 batches x 8 loads in flight
#pragma unroll
        for (int j = 0; j < 8; ++j)
          buf[j] = *(const float2*)&sp[(size_t)((kb * 8 + j) * 2) * (HO * WO)];
#pragma unroll
        for (int j = 0; j < 8; ++j) { sx += buf[j].x; sy += buf[j].y; }
      }
    }
    resr2[rr][2 * p][half]     = sx;
    resr2[rr][2 * p + 1][half] = sy;
  } else {
    const int t2 = tid - 384;                 // 0..127 (waves 6,7)
#pragma unroll
    for (int u = 0; u < 8; ++u) {             // x: 1024 quad-units
      const int i = u * 128 + t2;
      const int c2 = i >> 5, q = i & 31;
      const int row = (q < 16) ? rlo : r1;
      const int col = (q & 15) * 4;
      const float* sp = x + ((size_t)(b * C + 2 * c2) * HI + row) * WI + col;
      const float4 lo = *(const float4*)sp;
      const float4 hi = *(const float4*)(sp + (size_t)HI * WI);
      uint4 pk;
      pk.x = packbf(lo.x, hi.x); pk.y = packbf(lo.y, hi.y);
      pk.z = packbf(lo.z, hi.z); pk.w = packbf(lo.w, hi.w);
      *(uint4*)&xP[c2 * 128 + q * 4] = pk;
    }
#pragma unroll
    for (int u = 0; u < 8; ++u) {             // ref row h: 1024 quad-units
      const int i = u * 128 + t2;
      const int c2 = i >> 5, q = i & 31;
      const float* sp = ref + ((size_t)(b * C + 2 * c2) * HO + h) * WO + q * 4;
      const float4 lo = *(const float4*)sp;
      const float4 hi = *(const float4*)(sp + (size_t)HO * WO);
      uint4 pk;
      pk.x = packbf(lo.x, hi.x); pk.y = packbf(lo.y, hi.y);
      pk.z = packbf(lo.z, hi.z); pk.w = packbf(lo.w, hi.w);
      *(uint4*)&refsP[c2 * 132 + q * 4] = pk;
    }
    if (t2 < 64) {
      float s = g1[t2] * rsqrtf(v1[t2] + 1e-5f);
      s_bs1[t2] = c1b[t2] * s + b1v[t2] - m1[t2] * s;
      s = g2[t2] * rsqrtf(v2[t2] + 1e-5f);
      s_bs2[t2] = c2b[t2] * s + b2v[t2] - m2[t2] * s;
    }
  }

  // pack weight fragments (loads issued at kernel start; long since landed)
  i32x4 fa0i, fa1i, fb0i, fb1i;
  {
    const float s1 = g1o * rsqrtf(v1o + 1e-5f);
    const float s2 = g2o * rsqrtf(v2o + 1e-5f);
    fa0i[0] = (int)packbf(wa0.x * s1, wa0.y * s1);
    fa0i[1] = (int)packbf(wa0.z * s1, wa0.w * s1);
    fa0i[2] = (int)packbf(wa1.x * s1, wa1.y * s1);
    fa0i[3] = (int)packbf(wa1.z * s1, wa1.w * s1);
    fa1i[0] = (int)packbf(wa2.x * s1, wa2.y * s1);
    fa1i[1] = (int)packbf(wa2.z * s1, wa2.w * s1);
    fa1i[2] = (int)packbf(wa3.x * s1, wa3.y * s1);
    fa1i[3] = (int)packbf(wa3.z * s1, wa3.w * s1);
    fb0i[0] = (int)packbf(wb0.x * s2, wb0.y * s2);
    fb0i[1] = (int)packbf(wb0.z * s2, wb0.w * s2);
    fb0i[2] = (int)packbf(wb1.x * s2, wb1.y * s2);
    fb0i[3] = (int)packbf(wb1.z * s2, wb1.w * s2);
    fb1i[0] = (int)packbf(wb2.x * s2, wb2.y * s2);
    fb1i[1] = (int)packbf(wb2.z * s2, wb2.w * s2);
    fb1i[2] = (int)packbf(wb3.x * s2, wb3.y * s2);
    fb1i[3] = (int)packbf(wb3.z * s2, wb3.w * s2);
  }
  const short8 fa0 = __builtin_bit_cast(short8, fa0i);
  const short8 fa1 = __builtin_bit_cast(short8, fa1i);
  const short8 fb0 = __builtin_bit_cast(short8, fb0i);
  const short8 fb1 = __builtin_bit_cast(short8, fb1i);
  __syncthreads();   // b1

  // ---------------- phase 2a: conv2 MFMA from refsP; mask -------------------
  f32x4 acc2[4];
#pragma unroll
  for (int t = 0; t < 4; ++t) {
    const int px = wp * 64 + t * 16 + ln;
    i32x4 b0, b1;
#pragma unroll
    for (int r = 0; r < 4; ++r) {
      b0[r] = (int)refsP[(lq * 4 + r) * 132 + px];
      b1[r] = (int)refsP[(16 + lq * 4 + r) * 132 + px];
    }
    acc2[t] = (f32x4){0.f, 0.f, 0.f, 0.f};
    acc2[t] = __builtin_amdgcn_mfma_f32_16x16x32_bf16(fb0, __builtin_bit_cast(short8, b0), acc2[t], 0, 0, 0);
    acc2[t] = __builtin_amdgcn_mfma_f32_16x16x32_bf16(fb1, __builtin_bit_cast(short8, b1), acc2[t], 0, 0, 0);
  }

  // mask: per-pixel 4 corner weights + den (threads 0..127)
  if (tid < 128) {
    const int w = tid;
    float u[9];
#pragma unroll
    for (int dh = 0; dh < 3; ++dh)
#pragma unroll
      for (int dw = 0; dw < 3; ++dw) {
        const int col = w + dw - 1;
        u[dh * 3 + dw] = (col >= 0 && col < 128)
            ? (resr2[dh][col][0] + resr2[dh][col][1]) * (1.f / 64.f) : 0.f;
      }
    float sum = u[0];
#pragma unroll
    for (int k = 1; k < 9; ++k) sum += u[k];
    const float ua = sum * (1.f / 9.f);
    const bool ui = (u[4] - ua) > 0.f;

    const int clo = (w >= 1) ? ((w - 1) >> 1) : 0;
    unsigned den = 0;
    unsigned wc0 = 0, wc1 = 0, wc2 = 0, wc3 = 0;
#pragma unroll
    for (int dh = 0; dh < 3; ++dh) {
      const int hh = h + dh - 1;
      const bool hv = (hh >= 0) && (hh < HO);
      const int rs = hv ? ((hh >> 1) - rlo) : 0;
#pragma unroll
      for (int dw = 0; dw < 3; ++dw) {
        const bool up = (u[dh * 3 + dw] - ua) > 0.f;
        const unsigned mk = (up == ui) ? 1u : 0u;
        den += mk;
        const int ww = w + dw - 1;
        const bool wv = (ww >= 0) && (ww < WO);
        const int cs = wv ? ((ww >> 1) - clo) : 0;
        const unsigned t = (hv && wv) ? mk : 0u;
        const unsigned t0 = (rs == 0) ? t : 0u;
        const unsigned t1 = (rs == 1) ? t : 0u;
        wc0 += (cs == 0) ? t0 : 0u;
        wc1 += (cs == 1) ? t0 : 0u;
        wc2 += (cs == 0) ? t1 : 0u;
        wc3 += (cs == 1) ? t1 : 0u;
      }
    }
    s_wcp[w] = wc0 | (wc1 << 4) | (wc2 << 8) | (wc3 << 12) | (den << 16);
  }
  __syncthreads();   // b2: refsP reads done -> safe to overwrite with y1 tile

  // ---------------- phase 2b: conv1 MFMA -> y1 tile -------------------------
  {
    float bs1a[4];
    *(float4*)bs1a = *(const float4*)&s_bs1[ob];
#pragma unroll
    for (int t = 0; t < 4; ++t) {
      const int px = wp * 64 + t * 16 + ln;   // rowsel*64 + col
      i32x4 b0, b1;
#pragma unroll
      for (int r = 0; r < 4; ++r) {
        b0[r] = (int)xP[(lq * 4 + r) * 128 + px];
        b1[r] = (int)xP[(16 + lq * 4 + r) * 128 + px];
      }
      f32x4 a = {0.f, 0.f, 0.f, 0.f};
      a = __builtin_amdgcn_mfma_f32_16x16x32_bf16(fa0, __builtin_bit_cast(short8, b0), a, 0, 0, 0);
      a = __builtin_amdgcn_mfma_f32_16x16x32_bf16(fa1, __builtin_bit_cast(short8, b1), a, 0, 0, 0);
#pragma unroll
      for (int r = 0; r < 4; ++r)
        y1c[(ob + r) * 132 + px] = relu(a[r] + bs1a[r]);
    }
  }
  __syncthreads();   // b3: y1 tile ready

  // ---------------- epilogue -------------------------------------------------
  float bs2a[4];
  *(float4*)bs2a = *(const float4*)&s_bs2[ob];

#pragma unroll
  for (int t = 0; t < 4; ++t) {
    const int px = wp * 64 + t * 16 + ln;
    const int cl = (px >= 1) ? ((px - 1) >> 1) : 0;
    int c1 = cl + 1; if (c1 > WI - 1) c1 = WI - 1;
    const unsigned pk = s_wcp[px];
    const float wc0 = (float)(pk & 15u);
    const float wc1 = (float)((pk >> 4) & 15u);
    const float wc2 = (float)((pk >> 8) & 15u);
    const float wc3 = (float)((pk >> 12) & 15u);
    const float inv = 1.f / ((float)((pk >> 16) & 15u) + 1e-6f);

    float* op = out + (size_t)(b * C + ob) * (HO * WO) + h * WO + px;
#pragma unroll
    for (int r = 0; r < 4; ++r) {
      const float n = wc0 * y1c[(ob + r) * 132 + cl]
                    + wc1 * y1c[(ob + r) * 132 + c1]
                    + wc2 * y1c[(ob + r) * 132 + 64 + cl]
                    + wc3 * y1c[(ob + r) * 132 + 64 + c1];
      op[(size_t)r * (HO * WO)] = n * inv + relu(acc2[t][r] + bs2a[r]);
    }
  }
}

// ---------------------------------------------------------------------------
extern "C" void kernel_launch(void* const* d_in, const int* in_sizes, int n_in,
                              void* d_out, int out_size, void* d_ws, size_t ws_size,
                              hipStream_t stream) {
  (void)in_sizes; (void)n_in; (void)out_size; (void)d_ws; (void)ws_size;
  const float* x   = (const float*)d_in[0];
  const float* ref = (const float*)d_in[1];
  const float* w1  = (const float*)d_in[2];
  const float* c1b = (const float*)d_in[3];
  const float* g1  = (const float*)d_in[4];
  const float* b1  = (const float*)d_in[5];
  const float* m1  = (const float*)d_in[6];
  const float* v1  = (const float*)d_in[7];
  const float* w2  = (const float*)d_in[8];
  const float* c2b = (const float*)d_in[9];
  const float* g2  = (const float*)d_in[10];
  const float* b2  = (const float*)d_in[11];
  const float* m2  = (const float*)d_in[12];
  const float* v2  = (const float*)d_in[13];
  float* out = (float*)d_out;

  k_all<<<B * HO, 512, 0, stream>>>(x, ref, w1, c1b, g1, b1, m1, v1,
                                    w2, c2b, g2, b2, m2, v2, out);
}

// Round 5
// 128.837 us; speedup vs baseline: 1.1167x; 1.0758x over previous
//
#include <hip/hip_runtime.h>

// Problem dims (hardcoded per reference setup_inputs):
//   x:   (8, 64, 64, 64)   fp32
//   ref: (8, 64, 128, 128) fp32
//   out: (8, 64, 128, 128) fp32
#define B   8
#define C   64
#define HI  64
#define WI  64
#define HO  128
#define WO  128

using short8 = __attribute__((ext_vector_type(8))) short;
using f32x4  = __attribute__((ext_vector_type(4))) float;
using i32x4  = __attribute__((ext_vector_type(4))) int;

__device__ __forceinline__ float relu(float v) { return v > 0.f ? v : 0.f; }

// round-to-nearest-even f32 -> bf16 (low 16 bits of result)
__device__ __forceinline__ unsigned bf16rne(float x) {
  unsigned u = __float_as_uint(x);
  u += 0x7FFFu + ((u >> 16) & 1u);
  return u >> 16;
}
// pack two f32 -> bf16 pair (lo in bits [15:0], hi in bits [31:16])
__device__ __forceinline__ unsigned packbf(float lo, float hi) {
  unsigned ua = __float_as_uint(lo); ua += 0x7FFFu + ((ua >> 16) & 1u);
  unsigned ub = __float_as_uint(hi); ub += 0x7FFFu + ((ub >> 16) & 1u);
  return (ua >> 16) | (ub & 0xFFFF0000u);
}

// ---------------------------------------------------------------------------
// Persistent-block pipelined kernel: 256 blocks (1 per CU), 512 threads,
// each block computes 4 consecutive output rows h = hbase..hbase+3 of batch b.
// b = bx&7 -> all of batch b's rows on XCD b (ref slice L2-resident).
//
// Pipeline per iteration it (row h = hbase+it):
//   A: ISSUE next row's global loads into regs (x row-pair quads, ref row
//      quads, one new resr gather row of 32 independent float2 chains).
//   C: compute current row from LDS buffers [it&1]: conv2 MFMA -> acc2 regs;
//      conv1 MFMA -> y1c (separate LDS, no aliasing barrier); mask -> s_wcp.
//   bA (__syncthreads; its vmcnt drain doubles as the prefetch wait)
//   D: epilogue -> out (global stores).
//   E: pack + ds_write prefetched data into buffers [it&1^1]; resr slot it+3.
//   bB (__syncthreads)
// Weights/biases loaded+packed ONCE per block (4 rows), in the prologue.
// All FP accumulation orders identical to the round-0 lineage (bit-exact).
// LDS = 108,544 B -> 1 block/CU by design (pipeline supplies the latency
// hiding that occupancy used to).
// ---------------------------------------------------------------------------
__global__ __launch_bounds__(512, 2) void k_all(
    const float* __restrict__ x,   const float* __restrict__ ref,
    const float* __restrict__ w1,  const float* __restrict__ c1b,
    const float* __restrict__ g1,  const float* __restrict__ b1v,
    const float* __restrict__ m1,  const float* __restrict__ v1,
    const float* __restrict__ w2,  const float* __restrict__ c2b,
    const float* __restrict__ g2,  const float* __restrict__ b2v,
    const float* __restrict__ m2,  const float* __restrict__ v2,
    float* __restrict__ out) {
  __shared__ __align__(16) float    y1c[64 * 132];       // conv1 out tile (f32)
  __shared__ __align__(16) unsigned xPb[2][32 * 132];    // x c-pair bf16, dbuf
  __shared__ __align__(16) unsigned refPb[2][32 * 132];  // ref c-pair bf16, dbuf
  __shared__ __align__(16) float    resr[6][128][2];     // rolling gather rows
  __shared__ unsigned s_wcp[128];                        // wc0..3 + den nibbles
  __shared__ float    s_bs1[64];
  __shared__ float    s_bs2[64];

  const int bx  = blockIdx.x;
  const int b     = bx & 7;          // XCD-affine batch
  const int hbase = (bx >> 3) * 4;   // 0,4,...,124
  const int tid = threadIdx.x;

  const int wid  = tid >> 6;          // 0..7
  const int lane = tid & 63;
  const int wo = wid & 3, wp = wid >> 2;   // o-tile, px-half
  const int lq = lane >> 4, ln = lane & 15;
  const int ob = wo * 16 + lq * 4;
  const int ow = wo * 16 + ln;        // weight row for A-fragments

  // ---- weight fragment loads issued first (once per block) -----------------
  const float4 wa0 = *(const float4*)&w1[ow * 64 + lq * 8];
  const float4 wa1 = *(const float4*)&w1[ow * 64 + lq * 8 + 4];
  const float4 wa2 = *(const float4*)&w1[ow * 64 + 32 + lq * 8];
  const float4 wa3 = *(const float4*)&w1[ow * 64 + 32 + lq * 8 + 4];
  const float4 wb0 = *(const float4*)&w2[ow * 64 + lq * 8];
  const float4 wb1 = *(const float4*)&w2[ow * 64 + lq * 8 + 4];
  const float4 wb2 = *(const float4*)&w2[ow * 64 + 32 + lq * 8];
  const float4 wb3 = *(const float4*)&w2[ow * 64 + 32 + lq * 8 + 4];
  const float g1o = g1[ow], v1o = v1[ow];
  const float g2o = g2[ow], v2o = v2[ow];

  // ---------------- prologue: stage row hbase into buffers[0] ---------------
  {
    const int rlo0 = (hbase >= 1) ? ((hbase - 1) >> 1) : 0;
    int r10 = rlo0 + 1; if (r10 > HI - 1) r10 = HI - 1;

    float4 pxl[2], pxh[2], prl[2], prh[2];
#pragma unroll
    for (int u = 0; u < 2; ++u) {           // 2 x-units + 2 ref-units / thread
      const int idq = u * 512 + tid;
      const int c2 = idq >> 5, q = idq & 31;
      const int xrow = (q < 16) ? rlo0 : r10;
      const int col = (q & 15) * 4;
      const float* sp = x + ((size_t)(b * C + 2 * c2) * HI + xrow) * WI + col;
      pxl[u] = *(const float4*)sp;
      pxh[u] = *(const float4*)(sp + (size_t)HI * WI);
      const float* rp = ref + ((size_t)(b * C + 2 * c2) * HO + hbase) * WO + q * 4;
      prl[u] = *(const float4*)rp;
      prh[u] = *(const float4*)(rp + (size_t)HO * WO);
    }
    // gather rows hbase-1..hbase+1 -> slots 0..2 (threads 0..383, 1 chain ea.)
    float2 pg[32];
    const int grr = tid >> 7;
    const int gp = (tid & 127) >> 1, ghalf = tid & 1;
    bool gok = false;
    if (tid < 384) {
      const int hh = hbase + grr - 1;
      if (hh >= 0 && hh < HO) {
        gok = true;
        const float* sp = ref + ((size_t)(b * C + ghalf) * HO + hh) * WO + 2 * gp;
#pragma unroll
        for (int k = 0; k < 32; ++k)
          pg[k] = *(const float2*)&sp[(size_t)(2 * k) * (HO * WO)];
      }
    }
    if (tid >= 448) {                        // biases (threads 448..511)
      const int t2 = tid - 448;
      float s = g1[t2] * rsqrtf(v1[t2] + 1e-5f);
      s_bs1[t2] = c1b[t2] * s + b1v[t2] - m1[t2] * s;
      s = g2[t2] * rsqrtf(v2[t2] + 1e-5f);
      s_bs2[t2] = c2b[t2] * s + b2v[t2] - m2[t2] * s;
    }
#pragma unroll
    for (int u = 0; u < 2; ++u) {           // pack + store staging
      const int idq = u * 512 + tid;
      const int c2 = idq >> 5, q = idq & 31;
      uint4 pk;
      pk.x = packbf(pxl[u].x, pxh[u].x); pk.y = packbf(pxl[u].y, pxh[u].y);
      pk.z = packbf(pxl[u].z, pxh[u].z); pk.w = packbf(pxl[u].w, pxh[u].w);
      *(uint4*)&xPb[0][c2 * 132 + q * 4] = pk;
      uint4 pr;
      pr.x = packbf(prl[u].x, prh[u].x); pr.y = packbf(prl[u].y, prh[u].y);
      pr.z = packbf(prl[u].z, prh[u].z); pr.w = packbf(prl[u].w, prh[u].w);
      *(uint4*)&refPb[0][c2 * 132 + q * 4] = pr;
    }
    if (tid < 384) {                         // sum (ascending, bit-exact) + store
      float sx = 0.f, sy = 0.f;
      if (gok) {
#pragma unroll
        for (int k = 0; k < 32; ++k) { sx += pg[k].x; sy += pg[k].y; }
      }
      resr[grr][2 * gp][ghalf]     = sx;
      resr[grr][2 * gp + 1][ghalf] = sy;
    }
  }

  // pack weight fragments (loads long since landed)
  i32x4 fa0i, fa1i, fb0i, fb1i;
  {
    const float s1 = g1o * rsqrtf(v1o + 1e-5f);
    const float s2 = g2o * rsqrtf(v2o + 1e-5f);
    fa0i[0] = (int)packbf(wa0.x * s1, wa0.y * s1);
    fa0i[1] = (int)packbf(wa0.z * s1, wa0.w * s1);
    fa0i[2] = (int)packbf(wa1.x * s1, wa1.y * s1);
    fa0i[3] = (int)packbf(wa1.z * s1, wa1.w * s1);
    fa1i[0] = (int)packbf(wa2.x * s1, wa2.y * s1);
    fa1i[1] = (int)packbf(wa2.z * s1, wa2.w * s1);
    fa1i[2] = (int)packbf(wa3.x * s1, wa3.y * s1);
    fa1i[3] = (int)packbf(wa3.z * s1, wa3.w * s1);
    fb0i[0] = (int)packbf(wb0.x * s2, wb0.y * s2);
    fb0i[1] = (int)packbf(wb0.z * s2, wb0.w * s2);
    fb0i[2] = (int)packbf(wb1.x * s2, wb1.y * s2);
    fb0i[3] = (int)packbf(wb1.z * s2, wb1.w * s2);
    fb1i[0] = (int)packbf(wb2.x * s2, wb2.y * s2);
    fb1i[1] = (int)packbf(wb2.z * s2, wb2.w * s2);
    fb1i[2] = (int)packbf(wb3.x * s2, wb3.y * s2);
    fb1i[3] = (int)packbf(wb3.z * s2, wb3.w * s2);
  }
  const short8 fa0 = __builtin_bit_cast(short8, fa0i);
  const short8 fa1 = __builtin_bit_cast(short8, fa1i);
  const short8 fb0 = __builtin_bit_cast(short8, fb0i);
  const short8 fb1 = __builtin_bit_cast(short8, fb1i);
  __syncthreads();   // prologue barrier

  float bs1a[4], bs2a[4];
  *(float4*)bs1a = *(const float4*)&s_bs1[ob];
  *(float4*)bs2a = *(const float4*)&s_bs2[ob];

  // ---------------- 4-row pipeline ------------------------------------------
#pragma unroll
  for (int it = 0; it < 4; ++it) {
    const int cur = it & 1, nxt = cur ^ 1;
    const int h = hbase + it;
    const int rloc = (h >= 1) ? ((h - 1) >> 1) : 0;

    // ---- A: issue next row's loads into regs -------------------------------
    float4 xl[2], xh[2], rl[2], rh[2];
    float2 g[32];
    bool gk = false;
    if (it < 3) {
      const int hn = h + 1;
      const int rlon = (hn - 1) >> 1;
      int r1n = rlon + 1; if (r1n > HI - 1) r1n = HI - 1;
#pragma unroll
      for (int u = 0; u < 2; ++u) {
        const int idq = u * 512 + tid;
        const int c2 = idq >> 5, q = idq & 31;
        const int xrow = (q < 16) ? rlon : r1n;
        const int col = (q & 15) * 4;
        const float* sp = x + ((size_t)(b * C + 2 * c2) * HI + xrow) * WI + col;
        xl[u] = *(const float4*)sp;
        xh[u] = *(const float4*)(sp + (size_t)HI * WI);
        const float* rp = ref + ((size_t)(b * C + 2 * c2) * HO + hn) * WO + q * 4;
        rl[u] = *(const float4*)rp;
        rh[u] = *(const float4*)(rp + (size_t)HO * WO);
      }
      if (tid < 128) {
        const int hh = hbase + it + 2;       // resr slot it+3
        if (hh < HO) {
          gk = true;
          const int p = tid >> 1, half = tid & 1;
          const float* sp = ref + ((size_t)(b * C + half) * HO + hh) * WO + 2 * p;
#pragma unroll
          for (int k = 0; k < 32; ++k)
            g[k] = *(const float2*)&sp[(size_t)(2 * k) * (HO * WO)];
        }
      }
    }

    // ---- C: conv2 MFMA from refPb[cur] -------------------------------------
    f32x4 acc2[4];
#pragma unroll
    for (int t = 0; t < 4; ++t) {
      const int px = wp * 64 + t * 16 + ln;
      i32x4 b0, b1;
#pragma unroll
      for (int r = 0; r < 4; ++r) {
        b0[r] = (int)refPb[cur][(lq * 4 + r) * 132 + px];
        b1[r] = (int)refPb[cur][(16 + lq * 4 + r) * 132 + px];
      }
      acc2[t] = (f32x4){0.f, 0.f, 0.f, 0.f};
      acc2[t] = __builtin_amdgcn_mfma_f32_16x16x32_bf16(fb0, __builtin_bit_cast(short8, b0), acc2[t], 0, 0, 0);
      acc2[t] = __builtin_amdgcn_mfma_f32_16x16x32_bf16(fb1, __builtin_bit_cast(short8, b1), acc2[t], 0, 0, 0);
    }
    // conv1 MFMA from xPb[cur] -> y1c (separate LDS, no aliasing barrier)
#pragma unroll
    for (int t = 0; t < 4; ++t) {
      const int px = wp * 64 + t * 16 + ln;   // rowsel*64 + col
      i32x4 b0, b1;
#pragma unroll
      for (int r = 0; r < 4; ++r) {
        b0[r] = (int)xPb[cur][(lq * 4 + r) * 132 + px];
        b1[r] = (int)xPb[cur][(16 + lq * 4 + r) * 132 + px];
      }
      f32x4 a = {0.f, 0.f, 0.f, 0.f};
      a = __builtin_amdgcn_mfma_f32_16x16x32_bf16(fa0, __builtin_bit_cast(short8, b0), a, 0, 0, 0);
      a = __builtin_amdgcn_mfma_f32_16x16x32_bf16(fa1, __builtin_bit_cast(short8, b1), a, 0, 0, 0);
#pragma unroll
      for (int r = 0; r < 4; ++r)
        y1c[(ob + r) * 132 + px] = relu(a[r] + bs1a[r]);
    }

    // mask: per-pixel 4 corner weights + den (threads 0..127)
    if (tid < 128) {
      const int w = tid;
      float u9[9];
#pragma unroll
      for (int dh = 0; dh < 3; ++dh)
#pragma unroll
        for (int dw = 0; dw < 3; ++dw) {
          const int col = w + dw - 1;
          u9[dh * 3 + dw] = (col >= 0 && col < 128)
              ? (resr[it + dh][col][0] + resr[it + dh][col][1]) * (1.f / 64.f) : 0.f;
        }
      float sum = u9[0];
#pragma unroll
      for (int k = 1; k < 9; ++k) sum += u9[k];
      const float ua = sum * (1.f / 9.f);
      const bool ui = (u9[4] - ua) > 0.f;

      const int clo = (w >= 1) ? ((w - 1) >> 1) : 0;
      unsigned den = 0;
      unsigned wc0 = 0, wc1 = 0, wc2 = 0, wc3 = 0;
#pragma unroll
      for (int dh = 0; dh < 3; ++dh) {
        const int hh = h + dh - 1;
        const bool hv = (hh >= 0) && (hh < HO);
        const int rs = hv ? ((hh >> 1) - rloc) : 0;
#pragma unroll
        for (int dw = 0; dw < 3; ++dw) {
          const bool up = (u9[dh * 3 + dw] - ua) > 0.f;
          const unsigned mk = (up == ui) ? 1u : 0u;
          den += mk;
          const int ww = w + dw - 1;
          const bool wv = (ww >= 0) && (ww < WO);
          const int cs = wv ? ((ww >> 1) - clo) : 0;
          const unsigned tm = (hv && wv) ? mk : 0u;
          const unsigned t0 = (rs == 0) ? tm : 0u;
          const unsigned t1 = (rs == 1) ? tm : 0u;
          wc0 += (cs == 0) ? t0 : 0u;
          wc1 += (cs == 1) ? t0 : 0u;
          wc2 += (cs == 0) ? t1 : 0u;
          wc3 += (cs == 1) ? t1 : 0u;
        }
      }
      s_wcp[w] = wc0 | (wc1 << 4) | (wc2 << 8) | (wc3 << 12) | (den << 16);
    }
    __syncthreads();   // bA: y1c + mask ready (also drains prefetch loads)

    // ---- D: epilogue -------------------------------------------------------
#pragma unroll
    for (int t = 0; t < 4; ++t) {
      const int px = wp * 64 + t * 16 + ln;
      const int cl = (px >= 1) ? ((px - 1) >> 1) : 0;
      int c1 = cl + 1; if (c1 > WI - 1) c1 = WI - 1;
      const unsigned pk = s_wcp[px];
      const float wc0 = (float)(pk & 15u);
      const float wc1 = (float)((pk >> 4) & 15u);
      const float wc2 = (float)((pk >> 8) & 15u);
      const float wc3 = (float)((pk >> 12) & 15u);
      const float inv = 1.f / ((float)((pk >> 16) & 15u) + 1e-6f);

      float* op = out + (size_t)(b * C + ob) * (HO * WO) + h * WO + px;
#pragma unroll
      for (int r = 0; r < 4; ++r) {
        const float n = wc0 * y1c[(ob + r) * 132 + cl]
                      + wc1 * y1c[(ob + r) * 132 + c1]
                      + wc2 * y1c[(ob + r) * 132 + 64 + cl]
                      + wc3 * y1c[(ob + r) * 132 + 64 + c1];
        op[(size_t)r * (HO * WO)] = n * inv + relu(acc2[t][r] + bs2a[r]);
      }
    }

    // ---- E: write prefetched next-row data ---------------------------------
    if (it < 3) {
#pragma unroll
      for (int u = 0; u < 2; ++u) {
        const int idq = u * 512 + tid;
        const int c2 = idq >> 5, q = idq & 31;
        uint4 pk;
        pk.x = packbf(xl[u].x, xh[u].x); pk.y = packbf(xl[u].y, xh[u].y);
        pk.z = packbf(xl[u].z, xh[u].z); pk.w = packbf(xl[u].w, xh[u].w);
        *(uint4*)&xPb[nxt][c2 * 132 + q * 4] = pk;
        uint4 pr;
        pr.x = packbf(rl[u].x, rh[u].x); pr.y = packbf(rl[u].y, rh[u].y);
        pr.z = packbf(rl[u].z, rh[u].z); pr.w = packbf(rl[u].w, rh[u].w);
        *(uint4*)&refPb[nxt][c2 * 132 + q * 4] = pr;
      }
      if (tid < 128) {
        float sx = 0.f, sy = 0.f;
        if (gk) {
#pragma unroll
          for (int k = 0; k < 32; ++k) { sx += g[k].x; sy += g[k].y; }
        }
        const int p = tid >> 1, half = tid & 1;
        resr[it + 3][2 * p][half]     = sx;
        resr[it + 3][2 * p + 1][half] = sy;
      }
      __syncthreads();   // bB: next-row buffers visible; y1c/s_wcp reads done
    }
  }
}

// ---------------------------------------------------------------------------
extern "C" void kernel_launch(void* const* d_in, const int* in_sizes, int n_in,
                              void* d_out, int out_size, void* d_ws, size_t ws_size,
                              hipStream_t stream) {
  (void)in_sizes; (void)n_in; (void)out_size; (void)d_ws; (void)ws_size;
  const float* x   = (const float*)d_in[0];
  const float* ref = (const float*)d_in[1];
  const float* w1  = (const float*)d_in[2];
  const float* c1b = (const float*)d_in[3];
  const float* g1  = (const float*)d_in[4];
  const float* b1  = (const float*)d_in[5];
  const float* m1  = (const float*)d_in[6];
  const float* v1  = (const float*)d_in[7];
  const float* w2  = (const float*)d_in[8];
  const float* c2b = (const float*)d_in[9];
  const float* g2  = (const float*)d_in[10];
  const float* b2  = (const float*)d_in[11];
  const float* m2  = (const float*)d_in[12];
  const float* v2  = (const float*)d_in[13];
  float* out = (float*)d_out;

  k_all<<<256, 512, 0, stream>>>(x, ref, w1, c1b, g1, b1, m1, v1,
                                 w2, c2b, g2, b2, m2, v2, out);
}

// Round 6
// 123.753 us; speedup vs baseline: 1.1626x; 1.0411x over previous
//
#include <hip/hip_runtime.h>

// Problem dims (hardcoded per reference setup_inputs):
//   x:   (8, 64, 64, 64)   fp32
//   ref: (8, 64, 128, 128) fp32
//   out: (8, 64, 128, 128) fp32
#define B   8
#define C   64
#define HI  64
#define WI  64
#define HO  128
#define WO  128

using short8 = __attribute__((ext_vector_type(8))) short;
using f32x4  = __attribute__((ext_vector_type(4))) float;
using i32x4  = __attribute__((ext_vector_type(4))) int;

__device__ __forceinline__ float relu(float v) { return v > 0.f ? v : 0.f; }

// round-to-nearest-even f32 -> bf16 (low 16 bits of result)
__device__ __forceinline__ unsigned bf16rne(float x) {
  unsigned u = __float_as_uint(x);
  u += 0x7FFFu + ((u >> 16) & 1u);
  return u >> 16;
}
// pack two f32 -> bf16 pair (lo in bits [15:0], hi in bits [31:16])
__device__ __forceinline__ unsigned packbf(float lo, float hi) {
  unsigned ua = __float_as_uint(lo); ua += 0x7FFFu + ((ua >> 16) & 1u);
  unsigned ub = __float_as_uint(hi); ub += 0x7FFFu + ((ub >> 16) & 1u);
  return (ua >> 16) | (ub & 0xFFFF0000u);
}

// ---------------------------------------------------------------------------
// Persistent-block pipelined kernel, PIXEL-MAJOR LDS layouts (all hot LDS
// traffic is ds_read_b128/ds_write_b128, no scalar fragment gathers).
// 256 blocks (1/CU), 512 threads; each block does 4 rows h=hbase..hbase+3 of
// batch b = bx&7 (XCD-affine).
//
// LDS (115.7 KB, 1 block/CU):
//   y1cT [128 px][68 ch] f32 : conv1 out; b128 write per t, b128 corner reads
//   xPT/refPT [2][128 px][36 c2] u32 bf16-pairs: B-fragment = i32x4 at
//       px*36 + lq*4 (+16) — one b128 instead of 8 scalar b32.
//   resr [6][128][2], rolling gather rows (bit-exact order from round 0).
// Staging ownership is px-major: thread (spx = tid&127, sc2g = tid>>7) loads
// 32 coalesced scalar dwords (held in regs across compute), packs to bf16 and
// writes 4 uint4 ds_writes in E. Same values/orders as before -> bit-exact.
// Pipeline per iteration: A issue next-row loads -> C conv2+conv1 MFMA + mask
// -> bA -> D epilogue -> E pack/write next buffers -> bB.
// ---------------------------------------------------------------------------
__global__ __launch_bounds__(512, 2) void k_all(
    const float* __restrict__ x,   const float* __restrict__ ref,
    const float* __restrict__ w1,  const float* __restrict__ c1b,
    const float* __restrict__ g1,  const float* __restrict__ b1v,
    const float* __restrict__ m1,  const float* __restrict__ v1,
    const float* __restrict__ w2,  const float* __restrict__ c2b,
    const float* __restrict__ g2,  const float* __restrict__ b2v,
    const float* __restrict__ m2,  const float* __restrict__ v2,
    float* __restrict__ out) {
  __shared__ __align__(16) float    y1cT[128 * 68];      // [px][ch]
  __shared__ __align__(16) unsigned xPT[2][128 * 36];    // [px][c2] bf16-pair
  __shared__ __align__(16) unsigned refPT[2][128 * 36];  // [px][c2] bf16-pair
  __shared__ __align__(16) float    resr[6][128][2];     // rolling gather rows
  __shared__ unsigned s_wcp[128];                        // wc0..3 + den nibbles
  __shared__ float    s_bs1[64];
  __shared__ float    s_bs2[64];

  const int bx  = blockIdx.x;
  const int b     = bx & 7;          // XCD-affine batch
  const int hbase = (bx >> 3) * 4;   // 0,4,...,124
  const int tid = threadIdx.x;

  const int wid  = tid >> 6;          // 0..7
  const int lane = tid & 63;
  const int wo = wid & 3, wp = wid >> 2;   // o-tile, px-half
  const int lq = lane >> 4, ln = lane & 15;
  const int ob = wo * 16 + lq * 4;
  const int ow = wo * 16 + ln;        // weight row for A-fragments

  // staging ownership (px-major)
  const int spx  = tid & 127;         // owned px
  const int sc2g = tid >> 7;          // c2 octet: c2 = sc2g*8 + c
  const int scol = spx & 63;          // x column
  const int ssel = spx >> 6;          // x row selector (0 -> rlo, 1 -> r1)

  // ---- weight fragment loads issued first (once per block) -----------------
  const float4 wa0 = *(const float4*)&w1[ow * 64 + lq * 8];
  const float4 wa1 = *(const float4*)&w1[ow * 64 + lq * 8 + 4];
  const float4 wa2 = *(const float4*)&w1[ow * 64 + 32 + lq * 8];
  const float4 wa3 = *(const float4*)&w1[ow * 64 + 32 + lq * 8 + 4];
  const float4 wb0 = *(const float4*)&w2[ow * 64 + lq * 8];
  const float4 wb1 = *(const float4*)&w2[ow * 64 + lq * 8 + 4];
  const float4 wb2 = *(const float4*)&w2[ow * 64 + 32 + lq * 8];
  const float4 wb3 = *(const float4*)&w2[ow * 64 + 32 + lq * 8 + 4];
  const float g1o = g1[ow], v1o = v1[ow];
  const float g2o = g2[ow], v2o = v2[ow];

  // ---------------- prologue: stage row hbase into buffers[0] ---------------
  {
    const int rlo0 = (hbase >= 1) ? ((hbase - 1) >> 1) : 0;
    int r10 = rlo0 + 1; if (r10 > HI - 1) r10 = HI - 1;

    float xv[16], rv[16];
    {
      const int xr = ssel ? r10 : rlo0;
      const float* xb = x + ((size_t)(b * C + sc2g * 16) * HI + xr) * WI + scol;
      const float* rb = ref + ((size_t)(b * C + sc2g * 16) * HO + hbase) * WO + spx;
#pragma unroll
      for (int c = 0; c < 8; ++c) {
        xv[2 * c]     = xb[(size_t)(2 * c) * (HI * WI)];
        xv[2 * c + 1] = xb[(size_t)(2 * c + 1) * (HI * WI)];
        rv[2 * c]     = rb[(size_t)(2 * c) * (HO * WO)];
        rv[2 * c + 1] = rb[(size_t)(2 * c + 1) * (HO * WO)];
      }
    }
    // gather rows hbase-1..hbase+1 -> slots 0..2 (threads 0..383, 1 chain ea.)
    float2 pg[32];
    const int grr = tid >> 7;
    const int gp = (tid & 127) >> 1, ghalf = tid & 1;
    bool gok = false;
    if (tid < 384) {
      const int hh = hbase + grr - 1;
      if (hh >= 0 && hh < HO) {
        gok = true;
        const float* sp = ref + ((size_t)(b * C + ghalf) * HO + hh) * WO + 2 * gp;
#pragma unroll
        for (int k = 0; k < 32; ++k)
          pg[k] = *(const float2*)&sp[(size_t)(2 * k) * (HO * WO)];
      }
    }
    if (tid >= 448) {                        // biases (threads 448..511)
      const int t2 = tid - 448;
      float s = g1[t2] * rsqrtf(v1[t2] + 1e-5f);
      s_bs1[t2] = c1b[t2] * s + b1v[t2] - m1[t2] * s;
      s = g2[t2] * rsqrtf(v2[t2] + 1e-5f);
      s_bs2[t2] = c2b[t2] * s + b2v[t2] - m2[t2] * s;
    }
    {
      uint4 u0, u1, v0, v1q;
      u0.x = packbf(xv[0], xv[1]);  u0.y = packbf(xv[2], xv[3]);
      u0.z = packbf(xv[4], xv[5]);  u0.w = packbf(xv[6], xv[7]);
      u1.x = packbf(xv[8], xv[9]);  u1.y = packbf(xv[10], xv[11]);
      u1.z = packbf(xv[12], xv[13]); u1.w = packbf(xv[14], xv[15]);
      v0.x = packbf(rv[0], rv[1]);  v0.y = packbf(rv[2], rv[3]);
      v0.z = packbf(rv[4], rv[5]);  v0.w = packbf(rv[6], rv[7]);
      v1q.x = packbf(rv[8], rv[9]); v1q.y = packbf(rv[10], rv[11]);
      v1q.z = packbf(rv[12], rv[13]); v1q.w = packbf(rv[14], rv[15]);
      *(uint4*)&xPT[0][spx * 36 + sc2g * 8]       = u0;
      *(uint4*)&xPT[0][spx * 36 + sc2g * 8 + 4]   = u1;
      *(uint4*)&refPT[0][spx * 36 + sc2g * 8]     = v0;
      *(uint4*)&refPT[0][spx * 36 + sc2g * 8 + 4] = v1q;
    }
    if (tid < 384) {                         // sum (ascending, bit-exact) + store
      float sx = 0.f, sy = 0.f;
      if (gok) {
#pragma unroll
        for (int k = 0; k < 32; ++k) { sx += pg[k].x; sy += pg[k].y; }
      }
      resr[grr][2 * gp][ghalf]     = sx;
      resr[grr][2 * gp + 1][ghalf] = sy;
    }
  }

  // pack weight fragments (loads long since landed)
  i32x4 fa0i, fa1i, fb0i, fb1i;
  {
    const float s1 = g1o * rsqrtf(v1o + 1e-5f);
    const float s2 = g2o * rsqrtf(v2o + 1e-5f);
    fa0i[0] = (int)packbf(wa0.x * s1, wa0.y * s1);
    fa0i[1] = (int)packbf(wa0.z * s1, wa0.w * s1);
    fa0i[2] = (int)packbf(wa1.x * s1, wa1.y * s1);
    fa0i[3] = (int)packbf(wa1.z * s1, wa1.w * s1);
    fa1i[0] = (int)packbf(wa2.x * s1, wa2.y * s1);
    fa1i[1] = (int)packbf(wa2.z * s1, wa2.w * s1);
    fa1i[2] = (int)packbf(wa3.x * s1, wa3.y * s1);
    fa1i[3] = (int)packbf(wa3.z * s1, wa3.w * s1);
    fb0i[0] = (int)packbf(wb0.x * s2, wb0.y * s2);
    fb0i[1] = (int)packbf(wb0.z * s2, wb0.w * s2);
    fb0i[2] = (int)packbf(wb1.x * s2, wb1.y * s2);
    fb0i[3] = (int)packbf(wb1.z * s2, wb1.w * s2);
    fb1i[0] = (int)packbf(wb2.x * s2, wb2.y * s2);
    fb1i[1] = (int)packbf(wb2.z * s2, wb2.w * s2);
    fb1i[2] = (int)packbf(wb3.x * s2, wb3.y * s2);
    fb1i[3] = (int)packbf(wb3.z * s2, wb3.w * s2);
  }
  const short8 fa0 = __builtin_bit_cast(short8, fa0i);
  const short8 fa1 = __builtin_bit_cast(short8, fa1i);
  const short8 fb0 = __builtin_bit_cast(short8, fb0i);
  const short8 fb1 = __builtin_bit_cast(short8, fb1i);
  __syncthreads();   // prologue barrier

  float bs1a[4], bs2a[4];
  *(float4*)bs1a = *(const float4*)&s_bs1[ob];
  *(float4*)bs2a = *(const float4*)&s_bs2[ob];

  // ---------------- 4-row pipeline ------------------------------------------
#pragma unroll
  for (int it = 0; it < 4; ++it) {
    const int cur = it & 1, nxt = cur ^ 1;
    const int h = hbase + it;
    const int rloc = (h >= 1) ? ((h - 1) >> 1) : 0;

    // ---- A: issue next row's loads into regs -------------------------------
    float xv[16], rv[16];
    float2 g[32];
    bool gk = false;
    if (it < 3) {
      const int hn = h + 1;
      const int rlon = (hn - 1) >> 1;
      int r1n = rlon + 1; if (r1n > HI - 1) r1n = HI - 1;
      const int xr = ssel ? r1n : rlon;
      const float* xb = x + ((size_t)(b * C + sc2g * 16) * HI + xr) * WI + scol;
      const float* rb = ref + ((size_t)(b * C + sc2g * 16) * HO + hn) * WO + spx;
#pragma unroll
      for (int c = 0; c < 8; ++c) {
        xv[2 * c]     = xb[(size_t)(2 * c) * (HI * WI)];
        xv[2 * c + 1] = xb[(size_t)(2 * c + 1) * (HI * WI)];
        rv[2 * c]     = rb[(size_t)(2 * c) * (HO * WO)];
        rv[2 * c + 1] = rb[(size_t)(2 * c + 1) * (HO * WO)];
      }
      if (tid < 128) {
        const int hh = hbase + it + 2;       // resr slot it+3
        if (hh < HO) {
          gk = true;
          const int p = tid >> 1, half = tid & 1;
          const float* sp = ref + ((size_t)(b * C + half) * HO + hh) * WO + 2 * p;
#pragma unroll
          for (int k = 0; k < 32; ++k)
            g[k] = *(const float2*)&sp[(size_t)(2 * k) * (HO * WO)];
        }
      }
    }

    // ---- C: conv2 MFMA from refPT[cur] (b128 fragments) --------------------
    f32x4 acc2[4];
#pragma unroll
    for (int t = 0; t < 4; ++t) {
      const int px = wp * 64 + t * 16 + ln;
      const i32x4 b0 = *(const i32x4*)&refPT[cur][px * 36 + lq * 4];
      const i32x4 b1 = *(const i32x4*)&refPT[cur][px * 36 + 16 + lq * 4];
      acc2[t] = (f32x4){0.f, 0.f, 0.f, 0.f};
      acc2[t] = __builtin_amdgcn_mfma_f32_16x16x32_bf16(fb0, __builtin_bit_cast(short8, b0), acc2[t], 0, 0, 0);
      acc2[t] = __builtin_amdgcn_mfma_f32_16x16x32_bf16(fb1, __builtin_bit_cast(short8, b1), acc2[t], 0, 0, 0);
    }
    // conv1 MFMA from xPT[cur] -> y1cT (b128 fragments, b128 store per t)
#pragma unroll
    for (int t = 0; t < 4; ++t) {
      const int px = wp * 64 + t * 16 + ln;   // rowsel*64 + col
      const i32x4 b0 = *(const i32x4*)&xPT[cur][px * 36 + lq * 4];
      const i32x4 b1 = *(const i32x4*)&xPT[cur][px * 36 + 16 + lq * 4];
      f32x4 a = {0.f, 0.f, 0.f, 0.f};
      a = __builtin_amdgcn_mfma_f32_16x16x32_bf16(fa0, __builtin_bit_cast(short8, b0), a, 0, 0, 0);
      a = __builtin_amdgcn_mfma_f32_16x16x32_bf16(fa1, __builtin_bit_cast(short8, b1), a, 0, 0, 0);
      f32x4 yv;
#pragma unroll
      for (int r = 0; r < 4; ++r) yv[r] = relu(a[r] + bs1a[r]);
      *(f32x4*)&y1cT[px * 68 + ob] = yv;
    }

    // mask: per-pixel 4 corner weights + den (threads 0..127)
    if (tid < 128) {
      const int w = tid;
      float u9[9];
#pragma unroll
      for (int dh = 0; dh < 3; ++dh)
#pragma unroll
        for (int dw = 0; dw < 3; ++dw) {
          const int col = w + dw - 1;
          u9[dh * 3 + dw] = (col >= 0 && col < 128)
              ? (resr[it + dh][col][0] + resr[it + dh][col][1]) * (1.f / 64.f) : 0.f;
        }
      float sum = u9[0];
#pragma unroll
      for (int k = 1; k < 9; ++k) sum += u9[k];
      const float ua = sum * (1.f / 9.f);
      const bool ui = (u9[4] - ua) > 0.f;

      const int clo = (w >= 1) ? ((w - 1) >> 1) : 0;
      unsigned den = 0;
      unsigned wc0 = 0, wc1 = 0, wc2 = 0, wc3 = 0;
#pragma unroll
      for (int dh = 0; dh < 3; ++dh) {
        const int hh = h + dh - 1;
        const bool hv = (hh >= 0) && (hh < HO);
        const int rs = hv ? ((hh >> 1) - rloc) : 0;
#pragma unroll
        for (int dw = 0; dw < 3; ++dw) {
          const bool up = (u9[dh * 3 + dw] - ua) > 0.f;
          const unsigned mk = (up == ui) ? 1u : 0u;
          den += mk;
          const int ww = w + dw - 1;
          const bool wv = (ww >= 0) && (ww < WO);
          const int cs = wv ? ((ww >> 1) - clo) : 0;
          const unsigned tm = (hv && wv) ? mk : 0u;
          const unsigned t0 = (rs == 0) ? tm : 0u;
          const unsigned t1 = (rs == 1) ? tm : 0u;
          wc0 += (cs == 0) ? t0 : 0u;
          wc1 += (cs == 1) ? t0 : 0u;
          wc2 += (cs == 0) ? t1 : 0u;
          wc3 += (cs == 1) ? t1 : 0u;
        }
      }
      s_wcp[w] = wc0 | (wc1 << 4) | (wc2 << 8) | (wc3 << 12) | (den << 16);
    }
    __syncthreads();   // bA: y1cT + mask ready (also drains prefetch loads)

    // ---- D: epilogue (b128 corner reads) -----------------------------------
#pragma unroll
    for (int t = 0; t < 4; ++t) {
      const int px = wp * 64 + t * 16 + ln;
      const int cl = (px >= 1) ? ((px - 1) >> 1) : 0;
      int c1 = cl + 1; if (c1 > WI - 1) c1 = WI - 1;
      const unsigned pk = s_wcp[px];
      const float wc0 = (float)(pk & 15u);
      const float wc1 = (float)((pk >> 4) & 15u);
      const float wc2 = (float)((pk >> 8) & 15u);
      const float wc3 = (float)((pk >> 12) & 15u);
      const float inv = 1.f / ((float)((pk >> 16) & 15u) + 1e-6f);

      const f32x4 a00 = *(const f32x4*)&y1cT[cl * 68 + ob];
      const f32x4 a01 = *(const f32x4*)&y1cT[c1 * 68 + ob];
      const f32x4 a10 = *(const f32x4*)&y1cT[(64 + cl) * 68 + ob];
      const f32x4 a11 = *(const f32x4*)&y1cT[(64 + c1) * 68 + ob];

      float* op = out + (size_t)(b * C + ob) * (HO * WO) + h * WO + px;
#pragma unroll
      for (int r = 0; r < 4; ++r) {
        const float n = wc0 * a00[r] + wc1 * a01[r]
                      + wc2 * a10[r] + wc3 * a11[r];
        op[(size_t)r * (HO * WO)] = n * inv + relu(acc2[t][r] + bs2a[r]);
      }
    }

    // ---- E: write prefetched next-row data ---------------------------------
    if (it < 3) {
      uint4 u0, u1, v0, v1q;
      u0.x = packbf(xv[0], xv[1]);  u0.y = packbf(xv[2], xv[3]);
      u0.z = packbf(xv[4], xv[5]);  u0.w = packbf(xv[6], xv[7]);
      u1.x = packbf(xv[8], xv[9]);  u1.y = packbf(xv[10], xv[11]);
      u1.z = packbf(xv[12], xv[13]); u1.w = packbf(xv[14], xv[15]);
      v0.x = packbf(rv[0], rv[1]);  v0.y = packbf(rv[2], rv[3]);
      v0.z = packbf(rv[4], rv[5]);  v0.w = packbf(rv[6], rv[7]);
      v1q.x = packbf(rv[8], rv[9]); v1q.y = packbf(rv[10], rv[11]);
      v1q.z = packbf(rv[12], rv[13]); v1q.w = packbf(rv[14], rv[15]);
      *(uint4*)&xPT[nxt][spx * 36 + sc2g * 8]       = u0;
      *(uint4*)&xPT[nxt][spx * 36 + sc2g * 8 + 4]   = u1;
      *(uint4*)&refPT[nxt][spx * 36 + sc2g * 8]     = v0;
      *(uint4*)&refPT[nxt][spx * 36 + sc2g * 8 + 4] = v1q;
      if (tid < 128) {
        float sx = 0.f, sy = 0.f;
        if (gk) {
#pragma unroll
          for (int k = 0; k < 32; ++k) { sx += g[k].x; sy += g[k].y; }
        }
        const int p = tid >> 1, half = tid & 1;
        resr[it + 3][2 * p][half]     = sx;
        resr[it + 3][2 * p + 1][half] = sy;
      }
      __syncthreads();   // bB: next-row buffers visible; y1cT/s_wcp reads done
    }
  }
}

// ---------------------------------------------------------------------------
extern "C" void kernel_launch(void* const* d_in, const int* in_sizes, int n_in,
                              void* d_out, int out_size, void* d_ws, size_t ws_size,
                              hipStream_t stream) {
  (void)in_sizes; (void)n_in; (void)out_size; (void)d_ws; (void)ws_size;
  const float* x   = (const float*)d_in[0];
  const float* ref = (const float*)d_in[1];
  const float* w1  = (const float*)d_in[2];
  const float* c1b = (const float*)d_in[3];
  const float* g1  = (const float*)d_in[4];
  const float* b1  = (const float*)d_in[5];
  const float* m1  = (const float*)d_in[6];
  const float* v1  = (const float*)d_in[7];
  const float* w2  = (const float*)d_in[8];
  const float* c2b = (const float*)d_in[9];
  const float* g2  = (const float*)d_in[10];
  const float* b2  = (const float*)d_in[11];
  const float* m2  = (const float*)d_in[12];
  const float* v2  = (const float*)d_in[13];
  float* out = (float*)d_out;

  k_all<<<256, 512, 0, stream>>>(x, ref, w1, c1b, g1, b1, m1, v1,
                                 w2, c2b, g2, b2, m2, v2, out);
}